// Round 6
// baseline (342.818 us; speedup 1.0000x reference)
//
#include <hip/hip_runtime.h>
#include <hip/hip_bf16.h>

// B=2, L=2048, hidden=2048, H=16, KV=4, D=128, WIN=512
// Pipeline:
//   1) fused cast x, Wq|Wk|Wv, Wo -> bf16 (one kernel)
//   2) qkv = x @ Wqkv^T   (MFMA GEMM, global_load_lds w=16, XOR-swizzled LDS)
//   3) RMSNorm(q,k)+RoPE scatter; q pre-scaled by 1/sqrt(D)*log2(e)
//   3b) transpose V (read from qkv) -> VT[2,4,128,2048]
//   4) sliding-window flash attention, S^T dataflow, 128-q blocks,
//      DMA+XOR-swizzled K/VT staging, kf/vf fragments shared by both q-groups
//   5) out = attn @ Wo^T  (fp32 out)

typedef unsigned short u16;
typedef unsigned int u32;
typedef __attribute__((ext_vector_type(8))) short bf16x8;
typedef __attribute__((ext_vector_type(4))) float f32x4;

#define AS1 __attribute__((address_space(1)))
#define AS3 __attribute__((address_space(3)))

#if __has_builtin(__builtin_amdgcn_exp2f)
#define EXP2(x) __builtin_amdgcn_exp2f(x)
#else
#define EXP2(x) exp2f(x)
#endif

__device__ __forceinline__ u16 f2b(float f) {
  union { float f; u32 u; } c; c.f = f;
  return (u16)((c.u + 0x8000u) >> 16);   // fast round; inputs bounded, no NaN/inf
}
__device__ __forceinline__ float b2f(u16 u) {
  union { u32 u; float f; } c; c.u = ((u32)u) << 16; return c.f;
}

// ---------------- fused fp32 -> bf16 casts ----------------
__global__ __launch_bounds__(256) void cvt_all(const float* __restrict__ x,
                                               const float* __restrict__ wq,
                                               const float* __restrict__ wk,
                                               const float* __restrict__ wv,
                                               const float* __restrict__ wo,
                                               u16* __restrict__ xb,
                                               u16* __restrict__ wqkvb,
                                               u16* __restrict__ wob) {
  int blk = blockIdx.x;
  const float* s; u16* d; int off;
  if (blk < 8192)       { s = x;  d = xb;              off = blk * 1024; }
  else if (blk < 12288) { s = wq; d = wqkvb;           off = (blk - 8192) * 1024; }
  else if (blk < 13312) { s = wk; d = wqkvb + 4194304; off = (blk - 12288) * 1024; }
  else if (blk < 14336) { s = wv; d = wqkvb + 5242880; off = (blk - 13312) * 1024; }
  else                  { s = wo; d = wob;             off = (blk - 14336) * 1024; }
  int i = off + threadIdx.x * 4;
  float4 v = *(const float4*)(s + i);
  ushort4 o;
  o.x = f2b(v.x); o.y = f2b(v.y); o.z = f2b(v.z); o.w = f2b(v.w);
  *(ushort4*)(d + i) = o;
}

// ---------------- bf16 GEMM: C[M,N] = A[M,K] @ B[N,K]^T --------------------
// 128x128 tile, BK=64, 4 waves (2x2), 4x4 16x16x32 MFMAs per wave.
// global_load_lds width=16 into XOR-swizzled [128][64] LDS.
template<int F32OUT>
__global__ __launch_bounds__(256) void gemm_bt(const u16* __restrict__ A,
                                               const u16* __restrict__ Bm,
                                               void* __restrict__ C,
                                               int M, int N, int K) {
  __shared__ u16 As[128][64];
  __shared__ u16 Bs[128][64];
  const int tid  = threadIdx.x;
  const int w    = tid >> 6, lane = tid & 63, quad = lane >> 4, l16 = lane & 15;
  const int wm   = w >> 1, wn = w & 1;
  const int m0   = blockIdx.y * 128, n0 = blockIdx.x * 128;

  f32x4 zero = {0.f, 0.f, 0.f, 0.f};
  f32x4 acc[4][4];
#pragma unroll
  for (int i = 0; i < 4; i++)
#pragma unroll
    for (int j = 0; j < 4; j++) acc[i][j] = zero;

  const int srow = lane >> 3;
  const int swz8 = ((lane & 7) ^ (lane >> 3)) * 8;

  for (int k0 = 0; k0 < K; k0 += 64) {
#pragma unroll
    for (int p = 0; p < 4; ++p) {
      int row = p * 32 + w * 8 + srow;
      __builtin_amdgcn_global_load_lds(
          (const AS1 void*)(A + (size_t)(m0 + row) * K + k0 + swz8),
          (AS3 void*)((char*)&As[0][0] + p * 4096 + w * 1024), 16, 0, 0);
      __builtin_amdgcn_global_load_lds(
          (const AS1 void*)(Bm + (size_t)(n0 + row) * K + k0 + swz8),
          (AS3 void*)((char*)&Bs[0][0] + p * 4096 + w * 1024), 16, 0, 0);
    }
    __syncthreads();
#pragma unroll
    for (int kk = 0; kk < 64; kk += 32) {
      const int cs = ((kk >> 3) + quad) ^ (l16 & 7);
      bf16x8 af[4], bfr[4];
#pragma unroll
      for (int i = 0; i < 4; i++)
        af[i] = *(const bf16x8*)((const char*)&As[0][0] +
                                 (wm * 64 + i * 16 + l16) * 128 + cs * 16);
#pragma unroll
      for (int j = 0; j < 4; j++)
        bfr[j] = *(const bf16x8*)((const char*)&Bs[0][0] +
                                  (wn * 64 + j * 16 + l16) * 128 + cs * 16);
#pragma unroll
      for (int i = 0; i < 4; i++)
#pragma unroll
        for (int j = 0; j < 4; j++)
          acc[i][j] = __builtin_amdgcn_mfma_f32_16x16x32_bf16(af[i], bfr[j], acc[i][j], 0, 0, 0);
    }
    __syncthreads();
  }

#pragma unroll
  for (int i = 0; i < 4; i++) {
#pragma unroll
    for (int r = 0; r < 4; r++) {
      int gr = m0 + wm * 64 + i * 16 + quad * 4 + r;
#pragma unroll
      for (int j = 0; j < 4; j++) {
        int gc = n0 + wn * 64 + j * 16 + l16;
        if (F32OUT) ((float*)C)[(size_t)gr * N + gc] = acc[i][j][r];
        else        ((u16*)C)[(size_t)gr * N + gc]   = f2b(acc[i][j][r]);
      }
    }
  }
}

// ---------------- RMSNorm + RoPE + layout scatter (q,k only) ---------------
__global__ __launch_bounds__(256) void rmsrope(const u16* __restrict__ qkv,
                                               const float* __restrict__ cosT,
                                               const float* __restrict__ sinT,
                                               const float* __restrict__ qw,
                                               const float* __restrict__ kw,
                                               u16* __restrict__ qo,
                                               u16* __restrict__ ko) {
  int wid  = blockIdx.x * 4 + (threadIdx.x >> 6);
  int lane = threadIdx.x & 63;
  int r  = wid / 20;
  int hh = wid % 20;
  int b = r >> 11, l = r & 2047;
  int cb = hh < 16 ? hh * 128 : 2048 + (hh - 16) * 128;
  const u16* src = qkv + (size_t)r * 3072 + cb;
  float v0 = b2f(src[lane]);
  float v1 = b2f(src[lane + 64]);
  float ss = v0 * v0 + v1 * v1;
#pragma unroll
  for (int off = 1; off < 64; off <<= 1) ss += __shfl_xor(ss, off, 64);
  float inv = rsqrtf(ss * (1.0f / 128.0f) + 1e-6f);
  const float* wt = hh < 16 ? qw : kw;
  float n0 = v0 * inv * wt[lane];
  float n1 = v1 * inv * wt[lane + 64];
  float c0 = cosT[l * 128 + lane],      c1 = cosT[l * 128 + 64 + lane];
  float s0 = sinT[l * 128 + lane],      s1 = sinT[l * 128 + 64 + lane];
  float o0 = n0 * c0 - n1 * s0;
  float o1 = n1 * c1 + n0 * s1;
  const float qscale = 0.08838834764831845f * 1.4426950408889634f; // 1/sqrt(D)*log2e
  u16* dst; size_t base;
  if (hh < 16) { dst = qo; base = ((size_t)(b * 16 + hh) * 2048 + l) * 128;
                 o0 *= qscale; o1 *= qscale; }
  else         { dst = ko; base = ((size_t)(b * 4 + (hh - 16)) * 2048 + l) * 128; }
  dst[base + lane]      = f2b(o0);
  dst[base + 64 + lane] = f2b(o1);
}

// -------- V transpose from qkv: v cols 2560.. -> VT[2,4,128,2048] ----------
__global__ __launch_bounds__(256) void transpose_v(const u16* __restrict__ qkv,
                                                   u16* __restrict__ dst) {
  __shared__ u16 T[64][72];
  const int lt = blockIdx.x, dt = blockIdx.y, bh = blockIdx.z;
  const int b = bh >> 2, kv = bh & 3;
  const u16* s = qkv + ((size_t)(b * 2048 + lt * 64)) * 3072 + 2560 + kv * 128 + dt * 64;
  u16*       d = dst + (size_t)bh * 128 * 2048 + (size_t)dt * 64 * 2048 + lt * 64;
  const int t = threadIdx.x;
  const int row = t >> 3, c8 = (t & 7) * 8;
#pragma unroll
  for (int p = 0; p < 2; ++p)
    *(uint4*)&T[p * 32 + row][c8] = *(const uint4*)(s + (size_t)(p * 32 + row) * 3072 + c8);
  __syncthreads();
#pragma unroll
  for (int p = 0; p < 2; ++p) {
    int dr = p * 32 + row;
    u16 o[8];
#pragma unroll
    for (int j = 0; j < 8; ++j) o[j] = T[c8 + j][dr];
    *(uint4*)(d + (size_t)dr * 2048 + c8) = *(uint4*)o;
  }
}

// ---------------- sliding-window flash attention (S^T, 128-q, shared frags)
// Block: 128 q rows (2 groups g of 64) x head x batch; 4 waves.
// K/VT staged via global_load_lds into XOR-swizzled unpadded LDS
// (chunk' = chunk ^ (row&7); fragment reads 2-way conflict-free).
// kf/vf fragments loaded once, consumed by both q-groups' MFMAs.
__global__ __launch_bounds__(256) void flash_swa(const u16* __restrict__ Q,
                                                 const u16* __restrict__ Kg,
                                                 const u16* __restrict__ VTg,
                                                 u16* __restrict__ Og) {
  constexpr int L = 2048, D = 128;
  __shared__ u16 Ks[64 * 128];   // [row][16 chunks], swizzled
  __shared__ u16 Vt[128 * 64];   // [row][8 chunks],  swizzled
  __shared__ u16 Ps[4][16][72];

  const int q0  = blockIdx.x * 128;
  const int h   = blockIdx.y;
  const int b   = blockIdx.z;
  const int tid = threadIdx.x;
  const int w = tid >> 6, lane = tid & 63, quad = lane >> 4, l16 = lane & 15;
  const int kvh = h >> 2;

  const u16* Qb  = Q   + (size_t)(b * 16 + h)  * L * D;
  const u16* Kb  = Kg  + (size_t)(b * 4 + kvh) * L * D;
  const u16* VTb = VTg + (size_t)(b * 4 + kvh) * D * L;

  bf16x8 qf[2][4];
#pragma unroll
  for (int g = 0; g < 2; ++g) {
    int qr = q0 + g * 64 + w * 16 + l16;
#pragma unroll
    for (int ks = 0; ks < 4; ++ks)
      qf[g][ks] = *(const bf16x8*)(Qb + (size_t)qr * D + ks * 32 + quad * 8);
  }

  f32x4 zero = {0.f, 0.f, 0.f, 0.f};
  f32x4 o[2][8];
#pragma unroll
  for (int g = 0; g < 2; ++g)
#pragma unroll
    for (int i = 0; i < 8; i++) o[g][i] = zero;
  float lrow[2] = {0.f, 0.f};

  int kt0   = q0 > 512 ? q0 - 512 : 0;
  int ktend = q0 + 128 + 512; if (ktend > L) ktend = L;

  // DMA lane-geometry (constant across tiles)
  const int krow_l = lane >> 4;                 // K: row within 4-row group
  const int kcol_l = lane & 15;                 // K: logical chunk
  const int vrow_l = lane >> 3;                 // V: row within 8-row group
  const int vcol_l = lane & 7;                  // V: logical chunk

  for (int kt = kt0; kt < ktend; kt += 64) {
    // ---- DMA stage K tile [64][128] swizzled: chunk' = chunk ^ (row&7) ----
#pragma unroll
    for (int p = 0; p < 4; ++p) {
      int row = p * 16 + w * 4 + krow_l;
      int c   = kcol_l ^ (row & 7);
      __builtin_amdgcn_global_load_lds(
          (const AS1 void*)(Kb + (size_t)(kt + row) * D + c * 8),
          (AS3 void*)((char*)Ks + p * 4096 + w * 1024), 16, 0, 0);
    }
    // ---- DMA stage VT tile [128][64] swizzled ----
#pragma unroll
    for (int p = 0; p < 4; ++p) {
      int row = p * 32 + w * 8 + vrow_l;
      int c   = vcol_l ^ (row & 7);
      __builtin_amdgcn_global_load_lds(
          (const AS1 void*)(VTb + (size_t)row * L + kt + c * 8),
          (AS3 void*)((char*)Vt + p * 4096 + w * 1024), 16, 0, 0);
    }
    __syncthreads();

    const bool act0 = (kt >= q0 - 512) && (kt <= q0 + 512);
    const bool act1 = (kt >= q0 - 448);   // qg1=q0+64: kt>=qg1-512; upper bound ktend covers

    // ---- S^T = K x Q^T, kf shared across groups ----
    f32x4 s[2][4];
#pragma unroll
    for (int g = 0; g < 2; ++g)
#pragma unroll
      for (int ct = 0; ct < 4; ct++) s[g][ct] = zero;
#pragma unroll
    for (int ks = 0; ks < 4; ++ks) {
      bf16x8 kf[4];
#pragma unroll
      for (int ct = 0; ct < 4; ++ct) {
        int cphys = ((ks * 4 + quad) ^ (l16 & 7));
        kf[ct] = *(const bf16x8*)((const char*)Ks + (ct * 16 + l16) * 256 + cphys * 16);
      }
      if (act0) {
#pragma unroll
        for (int ct = 0; ct < 4; ++ct)
          s[0][ct] = __builtin_amdgcn_mfma_f32_16x16x32_bf16(kf[ct], qf[0][ks], s[0][ct], 0, 0, 0);
      }
      if (act1) {
#pragma unroll
        for (int ct = 0; ct < 4; ++ct)
          s[1][ct] = __builtin_amdgcn_mfma_f32_16x16x32_bf16(kf[ct], qf[1][ks], s[1][ct], 0, 0, 0);
      }
    }

    // ---- softmax per group; Ps round-trip -> pf (A-layout) ----
    bf16x8 pf[2][2];
#pragma unroll
    for (int g = 0; g < 2; ++g) {
      if (g == 0 ? !act0 : !act1) continue;
      const int qg = q0 + g * 64;
      const int qi = qg + w * 16 + l16;
      bool need_mask = (kt + 448 < qg) || (kt > qg + 448);
      float psum = 0.f;
#pragma unroll
      for (int ct = 0; ct < 4; ct++) {
        u16 ph[4];
#pragma unroll
        for (int r = 0; r < 4; r++) {
          float x = s[g][ct][r];
          if (need_mask) {
            int ki = kt + ct * 16 + quad * 4 + r;
            int dd = qi - ki; if (dd < 0) dd = -dd;
            if (dd > 512) x = -__builtin_inff();
          }
          float p = EXP2(x);
          psum += p;
          ph[r] = f2b(p);
        }
        uint2 pk;
        pk.x = (u32)ph[0] | ((u32)ph[1] << 16);
        pk.y = (u32)ph[2] | ((u32)ph[3] << 16);
        *(uint2*)&Ps[w][l16][ct * 16 + quad * 4] = pk;
      }
      psum += __shfl_xor(psum, 16, 64);
      psum += __shfl_xor(psum, 32, 64);
      lrow[g] += psum;
#pragma unroll
      for (int ks2 = 0; ks2 < 2; ++ks2)
        pf[g][ks2] = *(const bf16x8*)&Ps[w][l16][ks2 * 32 + quad * 8];
    }

    // ---- O += P V, vf shared across groups ----
#pragma unroll
    for (int dt = 0; dt < 8; ++dt) {
      bf16x8 vf[2];
#pragma unroll
      for (int ks2 = 0; ks2 < 2; ++ks2) {
        int cphys = ((ks2 * 4 + quad) ^ (l16 & 7));
        vf[ks2] = *(const bf16x8*)((const char*)Vt + (dt * 16 + l16) * 128 + cphys * 16);
      }
      if (act0) {
#pragma unroll
        for (int ks2 = 0; ks2 < 2; ++ks2)
          o[0][dt] = __builtin_amdgcn_mfma_f32_16x16x32_bf16(pf[0][ks2], vf[ks2], o[0][dt], 0, 0, 0);
      }
      if (act1) {
#pragma unroll
        for (int ks2 = 0; ks2 < 2; ++ks2)
          o[1][dt] = __builtin_amdgcn_mfma_f32_16x16x32_bf16(pf[1][ks2], vf[ks2], o[1][dt], 0, 0, 0);
      }
    }
    __syncthreads();
  }

  // ---- epilogue ----
#pragma unroll
  for (int g = 0; g < 2; ++g) {
#pragma unroll
    for (int r = 0; r < 4; r++) {
      float lv  = __shfl(lrow[g], (lane & 48) + quad * 4 + r, 64);
      float inv = 1.0f / lv;
      int qr = q0 + g * 64 + w * 16 + quad * 4 + r;
      size_t base = ((size_t)(b * L + qr)) * 2048 + h * 128;
#pragma unroll
      for (int dt = 0; dt < 8; dt++)
        Og[base + dt * 16 + l16] = f2b(o[g][dt][r] * inv);
    }
  }
}

// ---------------- launch ----------------
extern "C" void kernel_launch(void* const* d_in, const int* in_sizes, int n_in,
                              void* d_out, int out_size, void* d_ws, size_t ws_size,
                              hipStream_t stream) {
  const float* x    = (const float*)d_in[0];
  const float* cosT = (const float*)d_in[1];
  const float* sinT = (const float*)d_in[2];
  const float* Wq   = (const float*)d_in[3];
  const float* Wk   = (const float*)d_in[4];
  const float* Wv   = (const float*)d_in[5];
  const float* Wo   = (const float*)d_in[6];
  const float* qw   = (const float*)d_in[7];
  const float* kw   = (const float*)d_in[8];

  char* ws = (char*)d_ws;
  u16* x_bf    = (u16*)(ws + 0);          // 16 MB  [4096,2048]
  u16* wqkv_bf = (u16*)(ws + 16777216);   // 12 MB  [3072,2048]  (dead after gemm1)
  u16* wo_bf   = (u16*)(ws + 29360128);   //  8 MB  [2048,2048]
  u16* qkv_bf  = (u16*)(ws + 37748736);   // 24 MB  [4096,3072]
  u16* q_bf    = (u16*)(ws + 62914560);   // 16 MB  [2,16,2048,128]
  u16* k_bf    = (u16*)(ws + 79691776);   //  4 MB  [2,4,2048,128]
  u16* vt_bf   = wqkv_bf;                 //  4 MB  [2,4,128,2048] (reuses wqkv)
  u16* attn_bf = x_bf;                    // 16 MB  [4096,2048]    (reuses x)

  cvt_all<<<18432, 256, 0, stream>>>(x, Wq, Wk, Wv, Wo, x_bf, wqkv_bf, wo_bf);
  gemm_bt<0><<<dim3(24, 32), 256, 0, stream>>>(x_bf, wqkv_bf, qkv_bf, 4096, 3072, 2048);
  rmsrope<<<20480, 256, 0, stream>>>(qkv_bf, cosT, sinT, qw, kw, q_bf, k_bf);
  transpose_v<<<dim3(32, 2, 8), 256, 0, stream>>>(qkv_bf, vt_bf);
  flash_swa<<<dim3(16, 16, 2), 256, 0, stream>>>(q_bf, k_bf, vt_bf, attn_bf);
  gemm_bt<1><<<dim3(16, 32), 256, 0, stream>>>(attn_bf, wo_bf, d_out, 4096, 2048, 2048);
}

// Round 7
// 314.180 us; speedup vs baseline: 1.0911x; 1.0911x over previous
//
#include <hip/hip_runtime.h>
#include <hip/hip_bf16.h>

// B=2, L=2048, hidden=2048, H=16, KV=4, D=128, WIN=512
// Pipeline:
//   1) fused cast x, Wq|Wk|Wv, Wo -> bf16 (one kernel)
//   2) qkv = x @ Wqkv^T   (MFMA GEMM, global_load_lds w=16, XOR-swizzled LDS,
//                          XCD-aware block swizzle for per-XCD L2 B-panel reuse)
//   3) RMSNorm(q,k)+RoPE scatter; q pre-scaled by 1/sqrt(D)*log2(e)
//   3b) transpose V (read from qkv) -> VT[2,4,128,2048]
//   4) sliding-window flash attention: R4 structure (64-q blocks, 1024 blocks,
//      manual padded LDS staging — best measured: 79.5us), raw v_exp_f32
//   5) out = attn @ Wo^T  (fp32 out)

typedef unsigned short u16;
typedef unsigned int u32;
typedef __attribute__((ext_vector_type(8))) short bf16x8;
typedef __attribute__((ext_vector_type(4))) float f32x4;

#define AS1 __attribute__((address_space(1)))
#define AS3 __attribute__((address_space(3)))

#if __has_builtin(__builtin_amdgcn_exp2f)
#define EXP2(x) __builtin_amdgcn_exp2f(x)
#else
#define EXP2(x) exp2f(x)
#endif

__device__ __forceinline__ u16 f2b(float f) {
  union { float f; u32 u; } c; c.f = f;
  return (u16)((c.u + 0x8000u) >> 16);   // fast round; inputs bounded, no NaN/inf
}
__device__ __forceinline__ float b2f(u16 u) {
  union { u32 u; float f; } c; c.u = ((u32)u) << 16; return c.f;
}

// ---------------- fused fp32 -> bf16 casts ----------------
__global__ __launch_bounds__(256) void cvt_all(const float* __restrict__ x,
                                               const float* __restrict__ wq,
                                               const float* __restrict__ wk,
                                               const float* __restrict__ wv,
                                               const float* __restrict__ wo,
                                               u16* __restrict__ xb,
                                               u16* __restrict__ wqkvb,
                                               u16* __restrict__ wob) {
  int blk = blockIdx.x;
  const float* s; u16* d; int off;
  if (blk < 8192)       { s = x;  d = xb;              off = blk * 1024; }
  else if (blk < 12288) { s = wq; d = wqkvb;           off = (blk - 8192) * 1024; }
  else if (blk < 13312) { s = wk; d = wqkvb + 4194304; off = (blk - 12288) * 1024; }
  else if (blk < 14336) { s = wv; d = wqkvb + 5242880; off = (blk - 13312) * 1024; }
  else                  { s = wo; d = wob;             off = (blk - 14336) * 1024; }
  int i = off + threadIdx.x * 4;
  float4 v = *(const float4*)(s + i);
  ushort4 o;
  o.x = f2b(v.x); o.y = f2b(v.y); o.z = f2b(v.z); o.w = f2b(v.w);
  *(ushort4*)(d + i) = o;
}

// ---------------- bf16 GEMM: C[M,N] = A[M,K] @ B[N,K]^T --------------------
// 128x128 tile, BK=64, 4 waves (2x2), 4x4 16x16x32 MFMAs per wave.
// global_load_lds width=16 into XOR-swizzled [128][64] LDS.
// XCD swizzle: cid -> (xcd = cid&7) owns contiguous N-group (gridDim.x/8
// column blocks) so B-panel slice (~1-1.6MB) stays resident in that XCD's L2.
template<int F32OUT>
__global__ __launch_bounds__(256) void gemm_bt(const u16* __restrict__ A,
                                               const u16* __restrict__ Bm,
                                               void* __restrict__ C,
                                               int M, int N, int K) {
  __shared__ u16 As[128][64];
  __shared__ u16 Bs[128][64];
  const int tid  = threadIdx.x;
  const int w    = tid >> 6, lane = tid & 63, quad = lane >> 4, l16 = lane & 15;
  const int wm   = w >> 1, wn = w & 1;

  // XCD-aware remap (requires gridDim.x % 8 == 0)
  const int cid = blockIdx.x + blockIdx.y * gridDim.x;
  const int per = gridDim.x >> 3;           // n-blocks per XCD
  const int xcd = cid & 7;
  const int loc = cid >> 3;
  const int nb  = xcd * per + (loc % per);
  const int mb  = loc / per;
  const int m0  = mb * 128, n0 = nb * 128;

  f32x4 zero = {0.f, 0.f, 0.f, 0.f};
  f32x4 acc[4][4];
#pragma unroll
  for (int i = 0; i < 4; i++)
#pragma unroll
    for (int j = 0; j < 4; j++) acc[i][j] = zero;

  const int srow = lane >> 3;
  const int swz8 = ((lane & 7) ^ (lane >> 3)) * 8;

  for (int k0 = 0; k0 < K; k0 += 64) {
#pragma unroll
    for (int p = 0; p < 4; ++p) {
      int row = p * 32 + w * 8 + srow;
      __builtin_amdgcn_global_load_lds(
          (const AS1 void*)(A + (size_t)(m0 + row) * K + k0 + swz8),
          (AS3 void*)((char*)&As[0][0] + p * 4096 + w * 1024), 16, 0, 0);
      __builtin_amdgcn_global_load_lds(
          (const AS1 void*)(Bm + (size_t)(n0 + row) * K + k0 + swz8),
          (AS3 void*)((char*)&Bs[0][0] + p * 4096 + w * 1024), 16, 0, 0);
    }
    __syncthreads();
#pragma unroll
    for (int kk = 0; kk < 64; kk += 32) {
      const int cs = ((kk >> 3) + quad) ^ (l16 & 7);
      bf16x8 af[4], bfr[4];
#pragma unroll
      for (int i = 0; i < 4; i++)
        af[i] = *(const bf16x8*)((const char*)&As[0][0] +
                                 (wm * 64 + i * 16 + l16) * 128 + cs * 16);
#pragma unroll
      for (int j = 0; j < 4; j++)
        bfr[j] = *(const bf16x8*)((const char*)&Bs[0][0] +
                                  (wn * 64 + j * 16 + l16) * 128 + cs * 16);
#pragma unroll
      for (int i = 0; i < 4; i++)
#pragma unroll
        for (int j = 0; j < 4; j++)
          acc[i][j] = __builtin_amdgcn_mfma_f32_16x16x32_bf16(af[i], bfr[j], acc[i][j], 0, 0, 0);
    }
    __syncthreads();
  }

#pragma unroll
  for (int i = 0; i < 4; i++) {
#pragma unroll
    for (int r = 0; r < 4; r++) {
      int gr = m0 + wm * 64 + i * 16 + quad * 4 + r;
#pragma unroll
      for (int j = 0; j < 4; j++) {
        int gc = n0 + wn * 64 + j * 16 + l16;
        if (F32OUT) ((float*)C)[(size_t)gr * N + gc] = acc[i][j][r];
        else        ((u16*)C)[(size_t)gr * N + gc]   = f2b(acc[i][j][r]);
      }
    }
  }
}

// ---------------- RMSNorm + RoPE + layout scatter (q,k only) ---------------
__global__ __launch_bounds__(256) void rmsrope(const u16* __restrict__ qkv,
                                               const float* __restrict__ cosT,
                                               const float* __restrict__ sinT,
                                               const float* __restrict__ qw,
                                               const float* __restrict__ kw,
                                               u16* __restrict__ qo,
                                               u16* __restrict__ ko) {
  int wid  = blockIdx.x * 4 + (threadIdx.x >> 6);
  int lane = threadIdx.x & 63;
  int r  = wid / 20;
  int hh = wid % 20;
  int b = r >> 11, l = r & 2047;
  int cb = hh < 16 ? hh * 128 : 2048 + (hh - 16) * 128;
  const u16* src = qkv + (size_t)r * 3072 + cb;
  float v0 = b2f(src[lane]);
  float v1 = b2f(src[lane + 64]);
  float ss = v0 * v0 + v1 * v1;
#pragma unroll
  for (int off = 1; off < 64; off <<= 1) ss += __shfl_xor(ss, off, 64);
  float inv = rsqrtf(ss * (1.0f / 128.0f) + 1e-6f);
  const float* wt = hh < 16 ? qw : kw;
  float n0 = v0 * inv * wt[lane];
  float n1 = v1 * inv * wt[lane + 64];
  float c0 = cosT[l * 128 + lane],      c1 = cosT[l * 128 + 64 + lane];
  float s0 = sinT[l * 128 + lane],      s1 = sinT[l * 128 + 64 + lane];
  float o0 = n0 * c0 - n1 * s0;
  float o1 = n1 * c1 + n0 * s1;
  const float qscale = 0.08838834764831845f * 1.4426950408889634f; // 1/sqrt(D)*log2e
  u16* dst; size_t base;
  if (hh < 16) { dst = qo; base = ((size_t)(b * 16 + hh) * 2048 + l) * 128;
                 o0 *= qscale; o1 *= qscale; }
  else         { dst = ko; base = ((size_t)(b * 4 + (hh - 16)) * 2048 + l) * 128; }
  dst[base + lane]      = f2b(o0);
  dst[base + 64 + lane] = f2b(o1);
}

// -------- V transpose from qkv: v cols 2560.. -> VT[2,4,128,2048] ----------
__global__ __launch_bounds__(256) void transpose_v(const u16* __restrict__ qkv,
                                                   u16* __restrict__ dst) {
  __shared__ u16 T[64][72];
  const int lt = blockIdx.x, dt = blockIdx.y, bh = blockIdx.z;
  const int b = bh >> 2, kv = bh & 3;
  const u16* s = qkv + ((size_t)(b * 2048 + lt * 64)) * 3072 + 2560 + kv * 128 + dt * 64;
  u16*       d = dst + (size_t)bh * 128 * 2048 + (size_t)dt * 64 * 2048 + lt * 64;
  const int t = threadIdx.x;
  const int row = t >> 3, c8 = (t & 7) * 8;
#pragma unroll
  for (int p = 0; p < 2; ++p)
    *(uint4*)&T[p * 32 + row][c8] = *(const uint4*)(s + (size_t)(p * 32 + row) * 3072 + c8);
  __syncthreads();
#pragma unroll
  for (int p = 0; p < 2; ++p) {
    int dr = p * 32 + row;
    u16 o[8];
#pragma unroll
    for (int j = 0; j < 8; ++j) o[j] = T[c8 + j][dr];
    *(uint4*)(d + (size_t)dr * 2048 + c8) = *(uint4*)o;
  }
}

// ---------------- sliding-window flash attention (R4 structure) ------------
// Block: 64 q rows x head x batch (1024 blocks = 4/CU); 4 waves.
// Wave w owns q rows w*16..+15. Manual padded LDS staging (conflict-free).
// S^T = K-frag(A) x Q-frag(B): lane holds S[q=l16][k=ct*16+quad*4+r].
// No max subtraction (RMSNorm => |s| <= 16.4 in log2 domain). Raw v_exp_f32.
__global__ __launch_bounds__(256) void flash_swa(const u16* __restrict__ Q,
                                                 const u16* __restrict__ Kg,
                                                 const u16* __restrict__ VTg,
                                                 u16* __restrict__ Og) {
  constexpr int L = 2048, D = 128;
  __shared__ u16 Ks[64][136];
  __shared__ u16 Vt[128][72];
  __shared__ u16 Ps[4][16][72];

  const int q0  = blockIdx.x * 64;
  const int h   = blockIdx.y;
  const int b   = blockIdx.z;
  const int tid = threadIdx.x;
  const int w = tid >> 6, lane = tid & 63, quad = lane >> 4, l16 = lane & 15;
  const int kvh = h >> 2;

  const u16* Qb  = Q   + (size_t)(b * 16 + h)  * L * D;
  const u16* Kb  = Kg  + (size_t)(b * 4 + kvh) * L * D;
  const u16* VTb = VTg + (size_t)(b * 4 + kvh) * D * L;

  bf16x8 qf[4];
  {
    int qr = q0 + w * 16 + l16;
#pragma unroll
    for (int ks = 0; ks < 4; ++ks)
      qf[ks] = *(const bf16x8*)(Qb + (size_t)qr * D + ks * 32 + quad * 8);
  }
  const int qi = q0 + w * 16 + l16;   // this lane's q row (S^T dataflow)

  f32x4 zero = {0.f, 0.f, 0.f, 0.f};
  f32x4 o[8];
#pragma unroll
  for (int i = 0; i < 8; i++) o[i] = zero;
  float lrow = 0.f;

  int kt0   = q0 > 512 ? q0 - 512 : 0;
  int ktend = q0 + 64 + 512; if (ktend > L) ktend = L;

  for (int kt = kt0; kt < ktend; kt += 64) {
    // ---- stage K tile [64 keys][128 d], padded ----
#pragma unroll
    for (int p = 0; p < 4; ++p) {
      int c = tid + p * 256;
      int row = c >> 4, c8 = (c & 15) * 8;
      *(uint4*)&Ks[row][c8] = *(const uint4*)(Kb + (size_t)(kt + row) * D + c8);
    }
    // ---- stage VT tile [128 d][64 keys], padded ----
#pragma unroll
    for (int p = 0; p < 4; ++p) {
      int c = tid + p * 256;
      int row = c >> 3, c8 = (c & 7) * 8;
      *(uint4*)&Vt[row][c8] = *(const uint4*)(VTb + (size_t)row * L + kt + c8);
    }
    __syncthreads();

    // ---- S^T = K x Q^T : s[ct] tile rows=k, cols=q ----
    f32x4 s[4];
#pragma unroll
    for (int ct = 0; ct < 4; ct++) s[ct] = zero;
#pragma unroll
    for (int ks = 0; ks < 4; ++ks) {
#pragma unroll
      for (int ct = 0; ct < 4; ++ct) {
        bf16x8 kf = *(const bf16x8*)&Ks[ct * 16 + l16][ks * 32 + quad * 8];
        s[ct] = __builtin_amdgcn_mfma_f32_16x16x32_bf16(kf, qf[ks], s[ct], 0, 0, 0);
      }
    }

    // ---- P = exp2(S^T) (no max-sub), in-lane psum, pack to Ps[q][k] ----
    bool need_mask = (kt + 448 < q0) || (kt > q0 + 448);
    float psum = 0.f;
#pragma unroll
    for (int ct = 0; ct < 4; ct++) {
      u16 ph[4];
#pragma unroll
      for (int r = 0; r < 4; r++) {
        float x = s[ct][r];
        if (need_mask) {
          int ki = kt + ct * 16 + quad * 4 + r;
          int dd = qi - ki; if (dd < 0) dd = -dd;
          if (dd > 512) x = -__builtin_inff();
        }
        float p = EXP2(x);
        psum += p;
        ph[r] = f2b(p);
      }
      uint2 pk;
      pk.x = (u32)ph[0] | ((u32)ph[1] << 16);
      pk.y = (u32)ph[2] | ((u32)ph[3] << 16);
      *(uint2*)&Ps[w][l16][ct * 16 + quad * 4] = pk;
    }
    psum += __shfl_xor(psum, 16, 64);
    psum += __shfl_xor(psum, 32, 64);
    lrow += psum;

    // ---- O += P V  (P as A-operand from per-wave LDS; no barrier needed) --
    bf16x8 pf[2];
#pragma unroll
    for (int ks2 = 0; ks2 < 2; ++ks2)
      pf[ks2] = *(const bf16x8*)&Ps[w][l16][ks2 * 32 + quad * 8];
#pragma unroll
    for (int dt = 0; dt < 8; ++dt) {
#pragma unroll
      for (int ks2 = 0; ks2 < 2; ++ks2) {
        bf16x8 vf = *(const bf16x8*)&Vt[dt * 16 + l16][ks2 * 32 + quad * 8];
        o[dt] = __builtin_amdgcn_mfma_f32_16x16x32_bf16(pf[ks2], vf, o[dt], 0, 0, 0);
      }
    }
    __syncthreads();
  }

  // ---- epilogue: fetch lrow for this lane's output rows, store ----
#pragma unroll
  for (int r = 0; r < 4; r++) {
    float lv  = __shfl(lrow, (lane & 48) + quad * 4 + r, 64);
    float inv = 1.0f / lv;
    int qr = q0 + w * 16 + quad * 4 + r;
    size_t base = ((size_t)(b * L + qr)) * 2048 + h * 128;
#pragma unroll
    for (int dt = 0; dt < 8; dt++)
      Og[base + dt * 16 + l16] = f2b(o[dt][r] * inv);
  }
}

// ---------------- launch ----------------
extern "C" void kernel_launch(void* const* d_in, const int* in_sizes, int n_in,
                              void* d_out, int out_size, void* d_ws, size_t ws_size,
                              hipStream_t stream) {
  const float* x    = (const float*)d_in[0];
  const float* cosT = (const float*)d_in[1];
  const float* sinT = (const float*)d_in[2];
  const float* Wq   = (const float*)d_in[3];
  const float* Wk   = (const float*)d_in[4];
  const float* Wv   = (const float*)d_in[5];
  const float* Wo   = (const float*)d_in[6];
  const float* qw   = (const float*)d_in[7];
  const float* kw   = (const float*)d_in[8];

  char* ws = (char*)d_ws;
  u16* x_bf    = (u16*)(ws + 0);          // 16 MB  [4096,2048]
  u16* wqkv_bf = (u16*)(ws + 16777216);   // 12 MB  [3072,2048]  (dead after gemm1)
  u16* wo_bf   = (u16*)(ws + 29360128);   //  8 MB  [2048,2048]
  u16* qkv_bf  = (u16*)(ws + 37748736);   // 24 MB  [4096,3072]
  u16* q_bf    = (u16*)(ws + 62914560);   // 16 MB  [2,16,2048,128]
  u16* k_bf    = (u16*)(ws + 79691776);   //  4 MB  [2,4,2048,128]
  u16* vt_bf   = wqkv_bf;                 //  4 MB  [2,4,128,2048] (reuses wqkv)
  u16* attn_bf = x_bf;                    // 16 MB  [4096,2048]    (reuses x)

  cvt_all<<<18432, 256, 0, stream>>>(x, Wq, Wk, Wv, Wo, x_bf, wqkv_bf, wo_bf);
  gemm_bt<0><<<dim3(24, 32), 256, 0, stream>>>(x_bf, wqkv_bf, qkv_bf, 4096, 3072, 2048);
  rmsrope<<<20480, 256, 0, stream>>>(qkv_bf, cosT, sinT, qw, kw, q_bf, k_bf);
  transpose_v<<<dim3(32, 2, 8), 256, 0, stream>>>(qkv_bf, vt_bf);
  flash_swa<<<dim3(32, 16, 2), 256, 0, stream>>>(q_bf, k_bf, vt_bf, attn_bf);
  gemm_bt<1><<<dim3(16, 32), 256, 0, stream>>>(attn_bf, wo_bf, d_out, 4096, 2048, 2048);
}